// Round 9
// baseline (278.475 us; speedup 1.0000x reference)
//
#include <hip/hip_runtime.h>
#include <math.h>

#define WIN 7
#define WPT 8               // windows per thread (one item per thread in kssim)
#define BLK 256
#define NB 2048             // grid for kmax_partial
#define FIX_SCALE 274877906944.0   // 2^38 (Q38 fixed point; |sum| < 2^24 -> fits i64)

__device__ __forceinline__ float max4(float4 v) {
    return fmaxf(fmaxf(v.x, v.y), fmaxf(v.z, v.w));
}

// SSIM for one window from plain sums. Pre-scaled constants:
// c1=49*C1, c1d=2*c1, c2a=21*C2, c2b=42*C2.
__device__ __forceinline__ float ssim_win(float P, float Q, float sxx, float syy, float sxy,
                                          float c1, float c1d, float c2a, float c2b) {
    float t1 = P * Q;
    float u  = fmaf(P, P, Q * Q);
    float A1 = fmaf(t1, 4.0f, c1d);          // 2*(2PQ + 49C1)
    float A2 = fmaf(sxy, 7.0f, c2a - t1);    // 7sxy - PQ + 21C2
    float B1 = u + c1;
    float B2 = fmaf(sxx + syy, 7.0f, c2b - u);
    return (A1 * A2) * __builtin_amdgcn_rcpf(B1 * B2);
}

__global__ __launch_bounds__(BLK) void kmax_partial(const float* __restrict__ y, int n,
                                                    float* __restrict__ outMax,
                                                    unsigned long long* __restrict__ accum,
                                                    unsigned int* __restrict__ counter) {
    if (blockIdx.x == 0 && threadIdx.x == 0) { *accum = 0ull; *counter = 0u; }
    const int gid = blockIdx.x * BLK + threadIdx.x;
    const int n4 = n >> 2;
    const int GS = NB * BLK;
    const float4* y4 = (const float4*)y;
    float m0 = -__builtin_huge_valf(), m1 = m0;
    int i = gid;
    for (; i + GS < n4; i += 2 * GS) {
        float4 a = y4[i];
        float4 b = y4[i + GS];
        m0 = fmaxf(m0, max4(a));
        m1 = fmaxf(m1, max4(b));
    }
    for (; i < n4; i += GS) m0 = fmaxf(m0, max4(y4[i]));
    for (int j = (n4 << 2) + gid; j < n; j += GS) m0 = fmaxf(m0, y[j]);
    float m = fmaxf(m0, m1);
    #pragma unroll
    for (int off = 32; off; off >>= 1) m = fmaxf(m, __shfl_xor(m, off));
    __shared__ float sm[4];
    if ((threadIdx.x & 63) == 0) sm[threadIdx.x >> 6] = m;
    __syncthreads();
    if (threadIdx.x == 0)
        outMax[blockIdx.x] = fmaxf(fmaxf(sm[0], sm[1]), fmaxf(sm[2], sm[3]));
}

__global__ __launch_bounds__(BLK) void kssim(const float* __restrict__ x,
                                             const float* __restrict__ y,
                                             const float* __restrict__ partMax, int n,
                                             int ninterior, int nw,
                                             unsigned long long* __restrict__ accum,
                                             unsigned int* __restrict__ counter,
                                             float* __restrict__ out) {
    const int tid = threadIdx.x;
    const int gid = blockIdx.x * BLK + tid;
    __shared__ float sm[4];

    // ---- issue this thread's 8 loads FIRST (before the partMax reduce) ----
    float4 x0, x1, x2, x3, y0, y1, y2, y3;
    const bool have = (gid < ninterior);
    if (have) {
        const float4* px = (const float4*)(x + gid * WPT);   // 32B-aligned
        x0 = px[0]; x1 = px[1]; x2 = px[2]; x3 = px[3];
        const float4* py = (const float4*)(y + gid * WPT);
        y0 = py[0]; y1 = py[1]; y2 = py[2]; y3 = py[3];
    }

    // ---- block-local finalize of max(y) (8 KB, L2/L3-hot; overlaps loads) ----
    float mm = -__builtin_huge_valf();
    #pragma unroll
    for (int i = 0; i < NB / BLK; i++) mm = fmaxf(mm, partMax[i * BLK + tid]);
    #pragma unroll
    for (int off = 32; off; off >>= 1) mm = fmaxf(mm, __shfl_xor(mm, off));
    if ((tid & 63) == 0) sm[tid >> 6] = mm;
    __syncthreads();
    const float dr = fmaxf(fmaxf(sm[0], sm[1]), fmaxf(sm[2], sm[3]));
    const float C1 = (0.01f * dr) * (0.01f * dr);
    const float C2 = (0.03f * dr) * (0.03f * dr);
    const float c1  = 49.0f * C1;
    const float c1d = 2.0f * c1;
    const float c2a = 21.0f * C2;
    const float c2b = 42.0f * C2;

    // ---- one item per thread: 8 windows from 16 register-resident floats ----
    float acc = 0.0f;
    if (have) {
        float xv[16] = {x0.x,x0.y,x0.z,x0.w, x1.x,x1.y,x1.z,x1.w,
                        x2.x,x2.y,x2.z,x2.w, x3.x,x3.y,x3.z,x3.w};
        float yv[16] = {y0.x,y0.y,y0.z,y0.w, y1.x,y1.y,y1.z,y1.w,
                        y2.x,y2.y,y2.z,y2.w, y3.x,y3.y,y3.z,y3.w};
        float P = 0.f, Q = 0.f, sxx = 0.f, syy = 0.f, sxy = 0.f;
        #pragma unroll
        for (int k = 0; k < WIN; k++) {
            float a = xv[k], b = yv[k];
            P += a; Q += b;
            sxx = fmaf(a, a, sxx);
            syy = fmaf(b, b, syy);
            sxy = fmaf(a, b, sxy);
        }
        #pragma unroll
        for (int j = 0; j < WPT; j++) {
            acc += ssim_win(P, Q, sxx, syy, sxy, c1, c1d, c2a, c2b);
            if (j < WPT - 1) {
                float ao = xv[j], an = xv[j + WIN];
                float bo = yv[j], bn = yv[j + WIN];
                P += an - ao;
                Q += bn - bo;
                sxx += fmaf(an, an, -(ao * ao));
                syy += fmaf(bn, bn, -(bo * bo));
                sxy += fmaf(an, bn, -(ao * bo));
            }
        }
    }
    // tail windows not covered by items (< WPT+1 of them): thread 0, scalar
    if (gid == 0) {
        for (int w = ninterior * WPT; w < nw; ++w) {
            float P = 0.f, Q = 0.f, sxx = 0.f, syy = 0.f, sxy = 0.f;
            for (int k = 0; k < WIN; k++) {
                float a = x[w + k], b = y[w + k];
                P += a; Q += b;
                sxx = fmaf(a, a, sxx);
                syy = fmaf(b, b, syy);
                sxy = fmaf(a, b, sxy);
            }
            acc += ssim_win(P, Q, sxx, syy, sxy, c1, c1d, c2a, c2b);
        }
    }

    // ---- block reduce + deterministic fixed-point global accumulate ----
    #pragma unroll
    for (int off = 32; off; off >>= 1) acc += __shfl_xor(acc, off);
    __syncthreads();                     // sm reuse
    if ((tid & 63) == 0) sm[tid >> 6] = acc;
    __syncthreads();
    if (tid == 0) {
        float bs = (sm[0] + sm[1]) + (sm[2] + sm[3]);
        long long q = (long long)rint((double)bs * FIX_SCALE);
        atomicAdd(accum, (unsigned long long)q);
        __threadfence();
        unsigned int prev = atomicAdd(counter, 1u);
        if (prev == (unsigned int)(gridDim.x - 1)) {   // last block finalizes
            unsigned long long tot = atomicAdd(accum, 0ull);
            double s = (double)(long long)tot / FIX_SCALE;
            out[0] = (float)(s / (double)nw);
        }
    }
}

extern "C" void kernel_launch(void* const* d_in, const int* in_sizes, int n_in,
                              void* d_out, int out_size, void* d_ws, size_t ws_size,
                              hipStream_t stream) {
    const float* x = (const float*)d_in[0];
    const float* y = (const float*)d_in[1];
    float* out = (float*)d_out;
    int n = in_sizes[0];
    int nw = n - (WIN - 1);
    int ninterior = (n >= 16) ? ((n - 16) / WPT + 1) : 0;
    int nblocks = (ninterior + BLK - 1) / BLK;
    if (nblocks < 1) nblocks = 1;

    unsigned long long* accum = (unsigned long long*)d_ws;        // 8 B
    unsigned int* counter = (unsigned int*)((char*)d_ws + 8);     // 4 B
    float* partMax = (float*)((char*)d_ws + 256);                 // NB floats

    kmax_partial<<<NB, BLK, 0, stream>>>(y, n, partMax, accum, counter);
    kssim<<<nblocks, BLK, 0, stream>>>(x, y, partMax, n, ninterior, nw,
                                       accum, counter, out);
}

// Round 10
// 49.414 us; speedup vs baseline: 5.6355x; 5.6355x over previous
//
#include <hip/hip_runtime.h>
#include <math.h>

#define WIN 7
#define WPT 8                   // windows per thread
#define BLK 256
#define TILEW (BLK * WPT)       // 2048 windows per tile (one tile per block)
#define TFLOATS (TILEW + 16)    // 2064 floats staged per array (516 float4)
#define NB 2048                 // kmax_partial grid
// LDS stagger: word(f) = f + 4*(f>>5)  (4 pad words per 32 floats).
// Keeps float4 alignment (f%4==0 -> word%4==0) and spreads the 32B-stride
// read pattern from 16-way to 4-way bank aliasing.
#define LWORDS (TFLOATS + 4 * ((TFLOATS + 31) / 32))   // 2064 + 260 = 2324

__device__ __forceinline__ int lidx(int f) { return f + ((f >> 5) << 2); }

__device__ __forceinline__ float max4(float4 v) {
    return fmaxf(fmaxf(v.x, v.y), fmaxf(v.z, v.w));
}

// SSIM for one window from plain sums. Pre-scaled constants:
// c1=49*C1, c1d=2*c1, c2a=21*C2, c2b=42*C2.
__device__ __forceinline__ float ssim_win(float P, float Q, float sxx, float syy, float sxy,
                                          float c1, float c1d, float c2a, float c2b) {
    float t1 = P * Q;
    float u  = fmaf(P, P, Q * Q);
    float A1 = fmaf(t1, 4.0f, c1d);          // 2*(2PQ + 49C1)
    float A2 = fmaf(sxy, 7.0f, c2a - t1);    // 7sxy - PQ + 21C2
    float B1 = u + c1;
    float B2 = fmaf(sxx + syy, 7.0f, c2b - u);
    return (A1 * A2) * __builtin_amdgcn_rcpf(B1 * B2);
}

__device__ __forceinline__ float4 gload(const float* __restrict__ p, int f4, int n) {
    int f = f4 * 4;
    if (f + 4 <= n) return *(const float4*)(p + f);
    float4 v = {0.f, 0.f, 0.f, 0.f};
    if (f + 0 < n) v.x = p[f + 0];
    if (f + 1 < n) v.y = p[f + 1];
    if (f + 2 < n) v.z = p[f + 2];
    return v;
}

__device__ __forceinline__ void store4(float* lds, int f, float4 v) {
    *(float4*)&lds[lidx(f)] = v;    // f%4==0 -> 16B aligned, no pad crossing
}

__global__ __launch_bounds__(BLK) void kmax_partial(const float* __restrict__ y, int n,
                                                    float* __restrict__ outMax) {
    const int gid = blockIdx.x * BLK + threadIdx.x;
    const int n4 = n >> 2;
    const int GS = NB * BLK;
    const float4* y4 = (const float4*)y;
    float m0 = -__builtin_huge_valf(), m1 = m0;
    int i = gid;
    for (; i + GS < n4; i += 2 * GS) {
        float4 a = y4[i];
        float4 b = y4[i + GS];
        m0 = fmaxf(m0, max4(a));
        m1 = fmaxf(m1, max4(b));
    }
    for (; i < n4; i += GS) m0 = fmaxf(m0, max4(y4[i]));
    for (int j = (n4 << 2) + gid; j < n; j += GS) m0 = fmaxf(m0, y[j]);
    float m = fmaxf(m0, m1);
    #pragma unroll
    for (int off = 32; off; off >>= 1) m = fmaxf(m, __shfl_xor(m, off));
    __shared__ float sm[4];
    if ((threadIdx.x & 63) == 0) sm[threadIdx.x >> 6] = m;
    __syncthreads();
    if (threadIdx.x == 0)
        outMax[blockIdx.x] = fmaxf(fmaxf(sm[0], sm[1]), fmaxf(sm[2], sm[3]));
}

__global__ __launch_bounds__(BLK) void kssim(const float* __restrict__ x,
                                             const float* __restrict__ y,
                                             const float* __restrict__ partMax, int n,
                                             int nw,
                                             float* __restrict__ blockSums) {
    const int tid = threadIdx.x;
    const int T = blockIdx.x * TILEW;
    __shared__ float lx[LWORDS], ly[LWORDS];
    __shared__ float sm[4];

    // ---- block-local finalize of max(y) (8 KB, L2/L3-hot) ----
    float mm = -__builtin_huge_valf();
    #pragma unroll
    for (int i = 0; i < NB / BLK; i++) mm = fmaxf(mm, partMax[i * BLK + tid]);
    #pragma unroll
    for (int off = 32; off; off >>= 1) mm = fmaxf(mm, __shfl_xor(mm, off));
    if ((tid & 63) == 0) sm[tid >> 6] = mm;
    __syncthreads();
    const float dr = fmaxf(fmaxf(sm[0], sm[1]), fmaxf(sm[2], sm[3]));
    const float C1 = (0.01f * dr) * (0.01f * dr);
    const float C2 = (0.03f * dr) * (0.03f * dr);
    const float c1  = 49.0f * C1;
    const float c1d = 2.0f * c1;
    const float c2a = 21.0f * C2;
    const float c2b = 42.0f * C2;

    // ---- stage tile: coalesced 16B-lane-stride loads, 1x traffic ----
    const bool full = (T + TFLOATS <= n);
    if (full) {
        const float4* px = (const float4*)(x + T);
        const float4* py = (const float4*)(y + T);
        float4 a0 = px[tid], a1 = px[tid + 256];
        float4 b0 = py[tid], b1 = py[tid + 256];
        float4 a2, b2;
        if (tid < TFLOATS / 4 - 512) { a2 = px[512 + tid]; b2 = py[512 + tid]; }
        store4(lx, 4 * tid, a0);
        store4(lx, 4 * (tid + 256), a1);
        store4(ly, 4 * tid, b0);
        store4(ly, 4 * (tid + 256), b1);
        if (tid < TFLOATS / 4 - 512) {
            store4(lx, 4 * (512 + tid), a2);
            store4(ly, 4 * (512 + tid), b2);
        }
    } else {
        const int t4 = T >> 2;
        for (int i = tid; i < TFLOATS / 4; i += BLK) {
            store4(lx, 4 * i, gload(x, t4 + i, n));
            store4(ly, 4 * i, gload(y, t4 + i, n));
        }
    }
    __syncthreads();

    // ---- compute 8 windows per thread from LDS (4x ds_read_b128 per array) ----
    float acc = 0.0f;
    {
        const int f0 = 8 * tid;
        float4 v0 = *(const float4*)&lx[lidx(f0)];
        float4 v1 = *(const float4*)&lx[lidx(f0 + 4)];
        float4 v2 = *(const float4*)&lx[lidx(f0 + 8)];
        float4 v3 = *(const float4*)&lx[lidx(f0 + 12)];
        float4 w0 = *(const float4*)&ly[lidx(f0)];
        float4 w1 = *(const float4*)&ly[lidx(f0 + 4)];
        float4 w2 = *(const float4*)&ly[lidx(f0 + 8)];
        float4 w3 = *(const float4*)&ly[lidx(f0 + 12)];
        float xv[16] = {v0.x,v0.y,v0.z,v0.w, v1.x,v1.y,v1.z,v1.w,
                        v2.x,v2.y,v2.z,v2.w, v3.x,v3.y,v3.z,v3.w};
        float yv[16] = {w0.x,w0.y,w0.z,w0.w, w1.x,w1.y,w1.z,w1.w,
                        w2.x,w2.y,w2.z,w2.w, w3.x,w3.y,w3.z,w3.w};

        float P = 0.f, Q = 0.f, sxx = 0.f, syy = 0.f, sxy = 0.f;
        #pragma unroll
        for (int k = 0; k < WIN; k++) {
            float a = xv[k], b = yv[k];
            P += a; Q += b;
            sxx = fmaf(a, a, sxx);
            syy = fmaf(b, b, syy);
            sxy = fmaf(a, b, sxy);
        }
        if (T + TILEW + (WIN - 1) <= n) {     // all 2048 windows valid
            #pragma unroll
            for (int j = 0; j < WPT; j++) {
                acc += ssim_win(P, Q, sxx, syy, sxy, c1, c1d, c2a, c2b);
                if (j < WPT - 1) {
                    float ao = xv[j], an = xv[j + WIN];
                    float bo = yv[j], bn = yv[j + WIN];
                    P += an - ao;
                    Q += bn - bo;
                    sxx += fmaf(an, an, -(ao * ao));
                    syy += fmaf(bn, bn, -(bo * bo));
                    sxy += fmaf(an, bn, -(ao * bo));
                }
            }
        } else {                               // last tile: per-window guard
            const int wbase = T + 8 * tid;
            #pragma unroll
            for (int j = 0; j < WPT; j++) {
                if (wbase + j < nw)
                    acc += ssim_win(P, Q, sxx, syy, sxy, c1, c1d, c2a, c2b);
                if (j < WPT - 1) {
                    float ao = xv[j], an = xv[j + WIN];
                    float bo = yv[j], bn = yv[j + WIN];
                    P += an - ao;
                    Q += bn - bo;
                    sxx += fmaf(an, an, -(ao * ao));
                    syy += fmaf(bn, bn, -(bo * bo));
                    sxy += fmaf(an, bn, -(ao * bo));
                }
            }
        }
    }

    // ---- block reduce -> blockSums (no atomics!) ----
    #pragma unroll
    for (int off = 32; off; off >>= 1) acc += __shfl_xor(acc, off);
    __syncthreads();                     // sm reuse
    if ((tid & 63) == 0) sm[tid >> 6] = acc;
    __syncthreads();
    if (tid == 0)
        blockSums[blockIdx.x] = (sm[0] + sm[1]) + (sm[2] + sm[3]);
}

__global__ __launch_bounds__(BLK) void kfinal(const float* __restrict__ blockSums, int nb,
                                              float* __restrict__ out, int nw) {
    double s = 0.0;
    for (int i = threadIdx.x; i < nb; i += BLK) s += (double)blockSums[i];
    #pragma unroll
    for (int off = 32; off; off >>= 1) s += __shfl_xor(s, off);
    __shared__ double sd[4];
    if ((threadIdx.x & 63) == 0) sd[threadIdx.x >> 6] = s;
    __syncthreads();
    if (threadIdx.x == 0)
        out[0] = (float)(((sd[0] + sd[1]) + (sd[2] + sd[3])) / (double)nw);
}

extern "C" void kernel_launch(void* const* d_in, const int* in_sizes, int n_in,
                              void* d_out, int out_size, void* d_ws, size_t ws_size,
                              hipStream_t stream) {
    const float* x = (const float*)d_in[0];
    const float* y = (const float*)d_in[1];
    float* out = (float*)d_out;
    int n = in_sizes[0];
    int nw = n - (WIN - 1);
    int ntiles = (nw + TILEW - 1) / TILEW;

    float* wsf = (float*)d_ws;
    float* partMax   = wsf;          // NB floats
    float* blockSums = wsf + NB;     // ntiles floats

    kmax_partial<<<NB, BLK, 0, stream>>>(y, n, partMax);
    kssim<<<ntiles, BLK, 0, stream>>>(x, y, partMax, n, nw, blockSums);
    kfinal<<<1, BLK, 0, stream>>>(blockSums, ntiles, out, nw);
}

// Round 11
// 46.395 us; speedup vs baseline: 6.0023x; 1.0651x over previous
//
#include <hip/hip_runtime.h>
#include <math.h>

#define WIN 7
#define WPT 8               // windows per thread (one item per thread in kssim)
#define BLK 256
#define NB 2048             // grid for kmax_partial

__device__ __forceinline__ float max4(float4 v) {
    return fmaxf(fmaxf(v.x, v.y), fmaxf(v.z, v.w));
}

// SSIM for one window from plain sums. Pre-scaled constants:
// c1=49*C1, c1d=2*c1, c2a=21*C2, c2b=42*C2.
__device__ __forceinline__ float ssim_win(float P, float Q, float sxx, float syy, float sxy,
                                          float c1, float c1d, float c2a, float c2b) {
    float t1 = P * Q;
    float u  = fmaf(P, P, Q * Q);
    float A1 = fmaf(t1, 4.0f, c1d);          // 2*(2PQ + 49C1)
    float A2 = fmaf(sxy, 7.0f, c2a - t1);    // 7sxy - PQ + 21C2
    float B1 = u + c1;
    float B2 = fmaf(sxx + syy, 7.0f, c2b - u);
    return (A1 * A2) * __builtin_amdgcn_rcpf(B1 * B2);
}

__global__ __launch_bounds__(BLK) void kmax_partial(const float* __restrict__ y, int n,
                                                    float* __restrict__ outMax) {
    const int gid = blockIdx.x * BLK + threadIdx.x;
    const int n4 = n >> 2;
    const int GS = NB * BLK;
    const float4* y4 = (const float4*)y;
    float m0 = -__builtin_huge_valf(), m1 = m0;
    int i = gid;
    for (; i + GS < n4; i += 2 * GS) {
        float4 a = y4[i];
        float4 b = y4[i + GS];
        m0 = fmaxf(m0, max4(a));
        m1 = fmaxf(m1, max4(b));
    }
    for (; i < n4; i += GS) m0 = fmaxf(m0, max4(y4[i]));
    for (int j = (n4 << 2) + gid; j < n; j += GS) m0 = fmaxf(m0, y[j]);
    float m = fmaxf(m0, m1);
    #pragma unroll
    for (int off = 32; off; off >>= 1) m = fmaxf(m, __shfl_xor(m, off));
    __shared__ float sm[4];
    if ((threadIdx.x & 63) == 0) sm[threadIdx.x >> 6] = m;
    __syncthreads();
    if (threadIdx.x == 0)
        outMax[blockIdx.x] = fmaxf(fmaxf(sm[0], sm[1]), fmaxf(sm[2], sm[3]));
}

__global__ __launch_bounds__(BLK) void kssim(const float* __restrict__ x,
                                             const float* __restrict__ y,
                                             const float* __restrict__ partMax, int n,
                                             int ninterior, int nw,
                                             float* __restrict__ blockSums) {
    const int tid = threadIdx.x;
    const int gid = blockIdx.x * BLK + tid;
    __shared__ float sm[4];

    // ---- issue this thread's 8 loads FIRST (latency overlaps partMax reduce) ----
    float4 x0, x1, x2, x3, y0, y1, y2, y3;
    const bool have = (gid < ninterior);
    if (have) {
        const float4* px = (const float4*)(x + gid * WPT);   // 32B-aligned
        x0 = px[0]; x1 = px[1]; x2 = px[2]; x3 = px[3];
        const float4* py = (const float4*)(y + gid * WPT);
        y0 = py[0]; y1 = py[1]; y2 = py[2]; y3 = py[3];
    }

    // ---- block-local finalize of max(y) (8 KB, L2/L3-hot) ----
    float mm = -__builtin_huge_valf();
    #pragma unroll
    for (int i = 0; i < NB / BLK; i++) mm = fmaxf(mm, partMax[i * BLK + tid]);
    #pragma unroll
    for (int off = 32; off; off >>= 1) mm = fmaxf(mm, __shfl_xor(mm, off));
    if ((tid & 63) == 0) sm[tid >> 6] = mm;
    __syncthreads();
    const float dr = fmaxf(fmaxf(sm[0], sm[1]), fmaxf(sm[2], sm[3]));
    const float C1 = (0.01f * dr) * (0.01f * dr);
    const float C2 = (0.03f * dr) * (0.03f * dr);
    const float c1  = 49.0f * C1;
    const float c1d = 2.0f * c1;
    const float c2a = 21.0f * C2;
    const float c2b = 42.0f * C2;

    // ---- one item per thread: 8 windows from 16 register-resident floats ----
    float acc = 0.0f;
    if (have) {
        float xv[16] = {x0.x,x0.y,x0.z,x0.w, x1.x,x1.y,x1.z,x1.w,
                        x2.x,x2.y,x2.z,x2.w, x3.x,x3.y,x3.z,x3.w};
        float yv[16] = {y0.x,y0.y,y0.z,y0.w, y1.x,y1.y,y1.z,y1.w,
                        y2.x,y2.y,y2.z,y2.w, y3.x,y3.y,y3.z,y3.w};
        float P = 0.f, Q = 0.f, sxx = 0.f, syy = 0.f, sxy = 0.f;
        #pragma unroll
        for (int k = 0; k < WIN; k++) {
            float a = xv[k], b = yv[k];
            P += a; Q += b;
            sxx = fmaf(a, a, sxx);
            syy = fmaf(b, b, syy);
            sxy = fmaf(a, b, sxy);
        }
        #pragma unroll
        for (int j = 0; j < WPT; j++) {
            acc += ssim_win(P, Q, sxx, syy, sxy, c1, c1d, c2a, c2b);
            if (j < WPT - 1) {
                float ao = xv[j], an = xv[j + WIN];
                float bo = yv[j], bn = yv[j + WIN];
                P += an - ao;
                Q += bn - bo;
                sxx += fmaf(an, an, -(ao * ao));
                syy += fmaf(bn, bn, -(bo * bo));
                sxy += fmaf(an, bn, -(ao * bo));
            }
        }
    }
    // tail windows not covered by items (< WPT+1 of them): thread 0, scalar
    if (gid == 0) {
        for (int w = ninterior * WPT; w < nw; ++w) {
            float P = 0.f, Q = 0.f, sxx = 0.f, syy = 0.f, sxy = 0.f;
            for (int k = 0; k < WIN; k++) {
                float a = x[w + k], b = y[w + k];
                P += a; Q += b;
                sxx = fmaf(a, a, sxx);
                syy = fmaf(b, b, syy);
                sxy = fmaf(a, b, sxy);
            }
            acc += ssim_win(P, Q, sxx, syy, sxy, c1, c1d, c2a, c2b);
        }
    }

    // ---- block reduce -> blockSums (NO atomics — they serialize at ~45ns/block) ----
    #pragma unroll
    for (int off = 32; off; off >>= 1) acc += __shfl_xor(acc, off);
    __syncthreads();                     // sm reuse
    if ((tid & 63) == 0) sm[tid >> 6] = acc;
    __syncthreads();
    if (tid == 0)
        blockSums[blockIdx.x] = (sm[0] + sm[1]) + (sm[2] + sm[3]);
}

__global__ __launch_bounds__(BLK) void kfinal(const float* __restrict__ blockSums, int nb,
                                              float* __restrict__ out, int nw) {
    double s = 0.0;
    for (int i = threadIdx.x; i < nb; i += BLK) s += (double)blockSums[i];
    #pragma unroll
    for (int off = 32; off; off >>= 1) s += __shfl_xor(s, off);
    __shared__ double sd[4];
    if ((threadIdx.x & 63) == 0) sd[threadIdx.x >> 6] = s;
    __syncthreads();
    if (threadIdx.x == 0)
        out[0] = (float)(((sd[0] + sd[1]) + (sd[2] + sd[3])) / (double)nw);
}

extern "C" void kernel_launch(void* const* d_in, const int* in_sizes, int n_in,
                              void* d_out, int out_size, void* d_ws, size_t ws_size,
                              hipStream_t stream) {
    const float* x = (const float*)d_in[0];
    const float* y = (const float*)d_in[1];
    float* out = (float*)d_out;
    int n = in_sizes[0];
    int nw = n - (WIN - 1);
    int ninterior = (n >= 16) ? ((n - 16) / WPT + 1) : 0;
    int nblocks = (ninterior + BLK - 1) / BLK;
    if (nblocks < 1) nblocks = 1;

    float* wsf = (float*)d_ws;
    float* partMax   = wsf;          // NB floats
    float* blockSums = wsf + NB;     // nblocks floats (8192)

    kmax_partial<<<NB, BLK, 0, stream>>>(y, n, partMax);
    kssim<<<nblocks, BLK, 0, stream>>>(x, y, partMax, n, ninterior, nw, blockSums);
    kfinal<<<1, BLK, 0, stream>>>(blockSums, nblocks, out, nw);
}

// Round 12
// 43.521 us; speedup vs baseline: 6.3986x; 1.0660x over previous
//
#include <hip/hip_runtime.h>
#include <math.h>

#define WIN 7
#define WPT 4               // windows per thread-item; 16B lane stride = coalesced
#define BLK 256
#define NB 2048             // grid for kmax_partial and kssim
#define GSTRIDE (NB * BLK)

__device__ __forceinline__ float max4(float4 v) {
    return fmaxf(fmaxf(v.x, v.y), fmaxf(v.z, v.w));
}

// SSIM for one window from plain sums. Pre-scaled constants:
// c1=49*C1, c1d=2*c1, c2a=21*C2, c2b=42*C2.
__device__ __forceinline__ float ssim_win(float P, float Q, float sxx, float syy, float sxy,
                                          float c1, float c1d, float c2a, float c2b) {
    float t1 = P * Q;
    float u  = fmaf(P, P, Q * Q);
    float A1 = fmaf(t1, 4.0f, c1d);          // 2*(2PQ + 49C1)
    float A2 = fmaf(sxy, 7.0f, c2a - t1);    // 7sxy - PQ + 21C2
    float B1 = u + c1;
    float B2 = fmaf(sxx + syy, 7.0f, c2b - u);
    return (A1 * A2) * __builtin_amdgcn_rcpf(B1 * B2);
}

// one item = 4 consecutive windows from 12 register-resident floats per array
__device__ __forceinline__ float compute_item(float4 x0, float4 x1, float4 x2,
                                              float4 y0, float4 y1, float4 y2,
                                              float c1, float c1d, float c2a, float c2b) {
    float xv[12] = {x0.x,x0.y,x0.z,x0.w, x1.x,x1.y,x1.z,x1.w, x2.x,x2.y,x2.z,x2.w};
    float yv[12] = {y0.x,y0.y,y0.z,y0.w, y1.x,y1.y,y1.z,y1.w, y2.x,y2.y,y2.z,y2.w};
    float P = 0.f, Q = 0.f, sxx = 0.f, syy = 0.f, sxy = 0.f;
    #pragma unroll
    for (int k = 0; k < WIN; k++) {
        float a = xv[k], b = yv[k];
        P += a; Q += b;
        sxx = fmaf(a, a, sxx);
        syy = fmaf(b, b, syy);
        sxy = fmaf(a, b, sxy);
    }
    float r = 0.f;
    #pragma unroll
    for (int j = 0; j < WPT; j++) {
        r += ssim_win(P, Q, sxx, syy, sxy, c1, c1d, c2a, c2b);
        if (j < WPT - 1) {
            float ao = xv[j], an = xv[j + WIN];
            float bo = yv[j], bn = yv[j + WIN];
            P += an - ao;
            Q += bn - bo;
            sxx += fmaf(an, an, -(ao * ao));
            syy += fmaf(bn, bn, -(bo * bo));
            sxy += fmaf(an, bn, -(ao * bo));
        }
    }
    return r;
}

__global__ __launch_bounds__(BLK) void kmax_partial(const float* __restrict__ y, int n,
                                                    float* __restrict__ outMax) {
    const int gid = blockIdx.x * BLK + threadIdx.x;
    const int n4 = n >> 2;
    const float4* y4 = (const float4*)y;
    float m0 = -__builtin_huge_valf(), m1 = m0;
    int i = gid;
    for (; i + GSTRIDE < n4; i += 2 * GSTRIDE) {
        float4 a = y4[i];
        float4 b = y4[i + GSTRIDE];
        m0 = fmaxf(m0, max4(a));
        m1 = fmaxf(m1, max4(b));
    }
    for (; i < n4; i += GSTRIDE) m0 = fmaxf(m0, max4(y4[i]));
    for (int j = (n4 << 2) + gid; j < n; j += GSTRIDE) m0 = fmaxf(m0, y[j]);
    float m = fmaxf(m0, m1);
    #pragma unroll
    for (int off = 32; off; off >>= 1) m = fmaxf(m, __shfl_xor(m, off));
    __shared__ float sm[4];
    if ((threadIdx.x & 63) == 0) sm[threadIdx.x >> 6] = m;
    __syncthreads();
    if (threadIdx.x == 0)
        outMax[blockIdx.x] = fmaxf(fmaxf(sm[0], sm[1]), fmaxf(sm[2], sm[3]));
}

__global__ __launch_bounds__(BLK) void kssim(const float* __restrict__ x,
                                             const float* __restrict__ y,
                                             const float* __restrict__ partMax, int n,
                                             int ninterior, int nfull, int rem,
                                             float* __restrict__ blockSums) {
    const int tid = threadIdx.x;
    const int gid = blockIdx.x * BLK + tid;
    __shared__ float sm[4];

    // ---- block-local finalize of max(y) (8 KB, L2/L3-hot) ----
    float mm = -__builtin_huge_valf();
    #pragma unroll
    for (int i = 0; i < NB / BLK; i++) mm = fmaxf(mm, partMax[i * BLK + tid]);
    #pragma unroll
    for (int off = 32; off; off >>= 1) mm = fmaxf(mm, __shfl_xor(mm, off));
    if ((tid & 63) == 0) sm[tid >> 6] = mm;
    __syncthreads();
    const float dr = fmaxf(fmaxf(sm[0], sm[1]), fmaxf(sm[2], sm[3]));
    const float C1 = (0.01f * dr) * (0.01f * dr);
    const float C2 = (0.03f * dr) * (0.03f * dr);
    const float c1  = 49.0f * C1;
    const float c1d = 2.0f * c1;
    const float c2a = 21.0f * C2;
    const float c2b = 42.0f * C2;

    // ---- main: fixed-trip-count prefetch pipeline; COALESCED 16B-stride loads ----
    float acc = 0.0f;
    int g = gid;
    float4 ax0, ax1, ax2, ay0, ay1, ay2;
    if (g < ninterior) {
        const float4* px = (const float4*)(x + g * WPT);   // lane stride 16B
        ax0 = px[0]; ax1 = px[1]; ax2 = px[2];             // overlapping halo loads
        const float4* py = (const float4*)(y + g * WPT);
        ay0 = py[0]; ay1 = py[1]; ay2 = py[2];
    }
    for (int k = 0; k < nfull; k++) {
        const int gn = g + GSTRIDE;
        const bool nextExists = (k + 1 < nfull) || (gid < rem);
        float4 bx0, bx1, bx2, by0, by1, by2;
        if (nextExists) {                 // issue next item's loads before compute
            const float4* px = (const float4*)(x + gn * WPT);
            bx0 = px[0]; bx1 = px[1]; bx2 = px[2];
            const float4* py = (const float4*)(y + gn * WPT);
            by0 = py[0]; by1 = py[1]; by2 = py[2];
        }
        acc += compute_item(ax0, ax1, ax2, ay0, ay1, ay2, c1, c1d, c2a, c2b);
        ax0 = bx0; ax1 = bx1; ax2 = bx2;
        ay0 = by0; ay1 = by1; ay2 = by2;
        g = gn;
    }
    if (gid < rem)   // prefetched tail item (or the prologue item when nfull==0)
        acc += compute_item(ax0, ax1, ax2, ay0, ay1, ay2, c1, c1d, c2a, c2b);

    // tail windows not covered by items (< WPT+1 of them): thread 0, scalar
    if (gid == 0) {
        const int nw = n - (WIN - 1);
        for (int w = ninterior * WPT; w < nw; ++w) {
            float P = 0.f, Q = 0.f, sxx = 0.f, syy = 0.f, sxy = 0.f;
            for (int k = 0; k < WIN; k++) {
                float a = x[w + k], b = y[w + k];
                P += a; Q += b;
                sxx = fmaf(a, a, sxx);
                syy = fmaf(b, b, syy);
                sxy = fmaf(a, b, sxy);
            }
            acc += ssim_win(P, Q, sxx, syy, sxy, c1, c1d, c2a, c2b);
        }
    }

    // ---- block reduce -> blockSums (no atomics: they serialize ~45ns/block) ----
    #pragma unroll
    for (int off = 32; off; off >>= 1) acc += __shfl_xor(acc, off);
    __syncthreads();          // sm reused
    if ((tid & 63) == 0) sm[tid >> 6] = acc;
    __syncthreads();
    if (tid == 0)
        blockSums[blockIdx.x] = (sm[0] + sm[1]) + (sm[2] + sm[3]);
}

__global__ __launch_bounds__(BLK) void kfinal(const float* __restrict__ blockSums, int nb,
                                              float* __restrict__ out, int nw) {
    double s = 0.0;
    for (int i = threadIdx.x; i < nb; i += BLK) s += (double)blockSums[i];
    #pragma unroll
    for (int off = 32; off; off >>= 1) s += __shfl_xor(s, off);
    __shared__ double sd[4];
    if ((threadIdx.x & 63) == 0) sd[threadIdx.x >> 6] = s;
    __syncthreads();
    if (threadIdx.x == 0)
        out[0] = (float)(((sd[0] + sd[1]) + (sd[2] + sd[3])) / (double)nw);
}

extern "C" void kernel_launch(void* const* d_in, const int* in_sizes, int n_in,
                              void* d_out, int out_size, void* d_ws, size_t ws_size,
                              hipStream_t stream) {
    const float* x = (const float*)d_in[0];
    const float* y = (const float*)d_in[1];
    float* out = (float*)d_out;
    int n = in_sizes[0];
    int nw = n - (WIN - 1);
    int ninterior = (n >= 12) ? ((n - 12) / WPT + 1) : 0;  // item g needs floats [4g,4g+12)
    int nfull = ninterior / GSTRIDE;
    int rem   = ninterior - nfull * GSTRIDE;

    float* wsf = (float*)d_ws;
    float* partMax   = wsf;          // NB floats
    float* blockSums = wsf + NB;     // NB floats

    kmax_partial<<<NB, BLK, 0, stream>>>(y, n, partMax);
    kssim<<<NB, BLK, 0, stream>>>(x, y, partMax, n, ninterior, nfull, rem, blockSums);
    kfinal<<<1, BLK, 0, stream>>>(blockSums, NB, out, nw);
}

// Round 13
// 40.438 us; speedup vs baseline: 6.8864x; 1.0762x over previous
//
#include <hip/hip_runtime.h>
#include <math.h>

#define WIN 7
#define WPT 8               // windows per thread-item; non-overlapping 32B loads
#define BLK 256
#define NB 2048             // grid for kmax_partial and kssim
#define GSTRIDE (NB * BLK)
#define FBLK 1024           // kfinal block size

__device__ __forceinline__ float max4(float4 v) {
    return fmaxf(fmaxf(v.x, v.y), fmaxf(v.z, v.w));
}

// SSIM for one window from plain sums. Pre-scaled constants:
// c1=49*C1, c1d=2*c1, c2a=21*C2, c2b=42*C2.
__device__ __forceinline__ float ssim_win(float P, float Q, float sxx, float syy, float sxy,
                                          float c1, float c1d, float c2a, float c2b) {
    float t1 = P * Q;
    float u  = fmaf(P, P, Q * Q);
    float A1 = fmaf(t1, 4.0f, c1d);          // 2*(2PQ + 49C1)
    float A2 = fmaf(sxy, 7.0f, c2a - t1);    // 7sxy - PQ + 21C2
    float B1 = u + c1;
    float B2 = fmaf(sxx + syy, 7.0f, c2b - u);
    return (A1 * A2) * __builtin_amdgcn_rcpf(B1 * B2);
}

// one item = WPT consecutive windows from 16 register-resident floats per array
__device__ __forceinline__ float compute_item(float4 x0, float4 x1, float4 x2, float4 x3,
                                              float4 y0, float4 y1, float4 y2, float4 y3,
                                              float c1, float c1d, float c2a, float c2b) {
    float xv[16] = {x0.x,x0.y,x0.z,x0.w, x1.x,x1.y,x1.z,x1.w,
                    x2.x,x2.y,x2.z,x2.w, x3.x,x3.y,x3.z,x3.w};
    float yv[16] = {y0.x,y0.y,y0.z,y0.w, y1.x,y1.y,y1.z,y1.w,
                    y2.x,y2.y,y2.z,y2.w, y3.x,y3.y,y3.z,y3.w};
    float P = 0.f, Q = 0.f, sxx = 0.f, syy = 0.f, sxy = 0.f;
    #pragma unroll
    for (int k = 0; k < WIN; k++) {
        float a = xv[k], b = yv[k];
        P += a; Q += b;
        sxx = fmaf(a, a, sxx);
        syy = fmaf(b, b, syy);
        sxy = fmaf(a, b, sxy);
    }
    float r = 0.f;
    #pragma unroll
    for (int j = 0; j < WPT; j++) {
        r += ssim_win(P, Q, sxx, syy, sxy, c1, c1d, c2a, c2b);
        if (j < WPT - 1) {
            float ao = xv[j], an = xv[j + WIN];
            float bo = yv[j], bn = yv[j + WIN];
            P += an - ao;
            Q += bn - bo;
            sxx += fmaf(an, an, -(ao * ao));
            syy += fmaf(bn, bn, -(bo * bo));
            sxy += fmaf(an, bn, -(ao * bo));
        }
    }
    return r;
}

__global__ __launch_bounds__(BLK) void kmax_partial(const float* __restrict__ y, int n,
                                                    float* __restrict__ outMax) {
    const int gid = blockIdx.x * BLK + threadIdx.x;
    const int n4 = n >> 2;
    const float4* y4 = (const float4*)y;
    float m0 = -__builtin_huge_valf(), m1 = m0;
    int i = gid;
    for (; i + GSTRIDE < n4; i += 2 * GSTRIDE) {
        float4 a = y4[i];
        float4 b = y4[i + GSTRIDE];
        m0 = fmaxf(m0, max4(a));
        m1 = fmaxf(m1, max4(b));
    }
    for (; i < n4; i += GSTRIDE) m0 = fmaxf(m0, max4(y4[i]));
    for (int j = (n4 << 2) + gid; j < n; j += GSTRIDE) m0 = fmaxf(m0, y[j]);
    float m = fmaxf(m0, m1);
    #pragma unroll
    for (int off = 32; off; off >>= 1) m = fmaxf(m, __shfl_xor(m, off));
    __shared__ float sm[4];
    if ((threadIdx.x & 63) == 0) sm[threadIdx.x >> 6] = m;
    __syncthreads();
    if (threadIdx.x == 0)
        outMax[blockIdx.x] = fmaxf(fmaxf(sm[0], sm[1]), fmaxf(sm[2], sm[3]));
}

__global__ __launch_bounds__(BLK) void kssim(const float* __restrict__ x,
                                             const float* __restrict__ y,
                                             const float* __restrict__ partMax, int n,
                                             int ninterior, int nfull, int rem,
                                             float* __restrict__ blockSums) {
    const int tid = threadIdx.x;
    const int gid = blockIdx.x * BLK + tid;
    __shared__ float sm[4];

    // ---- issue prologue item's loads FIRST: memory stream starts immediately,
    //      latency hides under the partMax pre-reduce below ----
    float4 ax0, ax1, ax2, ax3, ay0, ay1, ay2, ay3;
    int g = gid;
    if (g < ninterior) {
        const float4* px = (const float4*)(x + g * WPT);   // 32B-aligned
        ax0 = px[0]; ax1 = px[1]; ax2 = px[2]; ax3 = px[3];
        const float4* py = (const float4*)(y + g * WPT);
        ay0 = py[0]; ay1 = py[1]; ay2 = py[2]; ay3 = py[3];
    }

    // ---- block-local finalize of max(y) (8 KB, L2/L3-hot) ----
    float mm = -__builtin_huge_valf();
    #pragma unroll
    for (int i = 0; i < NB / BLK; i++) mm = fmaxf(mm, partMax[i * BLK + tid]);
    #pragma unroll
    for (int off = 32; off; off >>= 1) mm = fmaxf(mm, __shfl_xor(mm, off));
    if ((tid & 63) == 0) sm[tid >> 6] = mm;
    __syncthreads();
    const float dr = fmaxf(fmaxf(sm[0], sm[1]), fmaxf(sm[2], sm[3]));
    const float C1 = (0.01f * dr) * (0.01f * dr);
    const float C2 = (0.03f * dr) * (0.03f * dr);
    const float c1  = 49.0f * C1;
    const float c1d = 2.0f * c1;
    const float c2a = 21.0f * C2;
    const float c2b = 42.0f * C2;

    // ---- fixed-trip-count depth-1 prefetch pipeline ----
    float acc = 0.0f;
    for (int k = 0; k < nfull; k++) {
        const int gn = g + GSTRIDE;
        const bool nextExists = (k + 1 < nfull) || (gid < rem);
        float4 bx0, bx1, bx2, bx3, by0, by1, by2, by3;
        if (nextExists) {                 // issue next item's loads before compute
            const float4* px = (const float4*)(x + gn * WPT);
            bx0 = px[0]; bx1 = px[1]; bx2 = px[2]; bx3 = px[3];
            const float4* py = (const float4*)(y + gn * WPT);
            by0 = py[0]; by1 = py[1]; by2 = py[2]; by3 = py[3];
        }
        acc += compute_item(ax0, ax1, ax2, ax3, ay0, ay1, ay2, ay3, c1, c1d, c2a, c2b);
        ax0 = bx0; ax1 = bx1; ax2 = bx2; ax3 = bx3;
        ay0 = by0; ay1 = by1; ay2 = by2; ay3 = by3;
        g = gn;
    }
    if (gid < rem)   // prefetched tail item (or the prologue item when nfull==0)
        acc += compute_item(ax0, ax1, ax2, ax3, ay0, ay1, ay2, ay3, c1, c1d, c2a, c2b);

    // tail windows not covered by items (< WPT+1 of them): thread 0, scalar
    if (gid == 0) {
        const int nw = n - (WIN - 1);
        for (int w = ninterior * WPT; w < nw; ++w) {
            float P = 0.f, Q = 0.f, sxx = 0.f, syy = 0.f, sxy = 0.f;
            for (int k = 0; k < WIN; k++) {
                float a = x[w + k], b = y[w + k];
                P += a; Q += b;
                sxx = fmaf(a, a, sxx);
                syy = fmaf(b, b, syy);
                sxy = fmaf(a, b, sxy);
            }
            acc += ssim_win(P, Q, sxx, syy, sxy, c1, c1d, c2a, c2b);
        }
    }

    // ---- block reduce -> blockSums (no atomics: serialize ~45ns/block) ----
    #pragma unroll
    for (int off = 32; off; off >>= 1) acc += __shfl_xor(acc, off);
    __syncthreads();          // sm reused
    if ((tid & 63) == 0) sm[tid >> 6] = acc;
    __syncthreads();
    if (tid == 0)
        blockSums[blockIdx.x] = (sm[0] + sm[1]) + (sm[2] + sm[3]);
}

__global__ __launch_bounds__(FBLK) void kfinal(const float* __restrict__ blockSums, int nb,
                                               float* __restrict__ out, int nw) {
    double s = 0.0;
    for (int i = threadIdx.x; i < nb; i += FBLK) s += (double)blockSums[i];
    #pragma unroll
    for (int off = 32; off; off >>= 1) s += __shfl_xor(s, off);
    __shared__ double sd[FBLK / 64];
    if ((threadIdx.x & 63) == 0) sd[threadIdx.x >> 6] = s;
    __syncthreads();
    if (threadIdx.x == 0) {
        double t = 0.0;
        #pragma unroll
        for (int i = 0; i < FBLK / 64; i++) t += sd[i];
        out[0] = (float)(t / (double)nw);
    }
}

extern "C" void kernel_launch(void* const* d_in, const int* in_sizes, int n_in,
                              void* d_out, int out_size, void* d_ws, size_t ws_size,
                              hipStream_t stream) {
    const float* x = (const float*)d_in[0];
    const float* y = (const float*)d_in[1];
    float* out = (float*)d_out;
    int n = in_sizes[0];
    int nw = n - (WIN - 1);
    int ninterior = (n >= 16) ? ((n - 16) / WPT + 1) : 0;  // item g needs floats [8g,8g+16)
    int nfull = ninterior / GSTRIDE;
    int rem   = ninterior - nfull * GSTRIDE;

    float* wsf = (float*)d_ws;
    float* partMax   = wsf;          // NB floats
    float* blockSums = wsf + NB;     // NB floats

    kmax_partial<<<NB, BLK, 0, stream>>>(y, n, partMax);
    kssim<<<NB, BLK, 0, stream>>>(x, y, partMax, n, ninterior, nfull, rem, blockSums);
    kfinal<<<1, FBLK, 0, stream>>>(blockSums, NB, out, nw);
}

// Round 15
// 39.395 us; speedup vs baseline: 7.0688x; 1.0265x over previous
//
#include <hip/hip_runtime.h>
#include <math.h>

#define WIN 7
#define WPT 8               // windows per thread-item; non-overlapping 32B loads
#define BLK 256             // kmax block
#define SBLK 512            // kssim block
#define NB 2048             // kmax grid
#define SNB 1024            // kssim grid (SNB*SBLK == NB*BLK threads)
#define GSTRIDE (NB * BLK)
#define FBLK 512            // kfinal block size

__device__ __forceinline__ float max4(float4 v) {
    return fmaxf(fmaxf(v.x, v.y), fmaxf(v.z, v.w));
}

// SSIM for one window from plain sums. Pre-scaled constants:
// c1=49*C1, c1d=2*c1, c2a=21*C2, c2b=42*C2.
__device__ __forceinline__ float ssim_win(float P, float Q, float sxx, float syy, float sxy,
                                          float c1, float c1d, float c2a, float c2b) {
    float t1 = P * Q;
    float u  = fmaf(P, P, Q * Q);
    float A1 = fmaf(t1, 4.0f, c1d);          // 2*(2PQ + 49C1)
    float A2 = fmaf(sxy, 7.0f, c2a - t1);    // 7sxy - PQ + 21C2
    float B1 = u + c1;
    float B2 = fmaf(sxx + syy, 7.0f, c2b - u);
    return (A1 * A2) * __builtin_amdgcn_rcpf(B1 * B2);
}

// one item = WPT consecutive windows from 16 register-resident floats per array
__device__ __forceinline__ float compute_item(float4 x0, float4 x1, float4 x2, float4 x3,
                                              float4 y0, float4 y1, float4 y2, float4 y3,
                                              float c1, float c1d, float c2a, float c2b) {
    float xv[16] = {x0.x,x0.y,x0.z,x0.w, x1.x,x1.y,x1.z,x1.w,
                    x2.x,x2.y,x2.z,x2.w, x3.x,x3.y,x3.z,x3.w};
    float yv[16] = {y0.x,y0.y,y0.z,y0.w, y1.x,y1.y,y1.z,y1.w,
                    y2.x,y2.y,y2.z,y2.w, y3.x,y3.y,y3.z,y3.w};
    float P = 0.f, Q = 0.f, sxx = 0.f, syy = 0.f, sxy = 0.f;
    #pragma unroll
    for (int k = 0; k < WIN; k++) {
        float a = xv[k], b = yv[k];
        P += a; Q += b;
        sxx = fmaf(a, a, sxx);
        syy = fmaf(b, b, syy);
        sxy = fmaf(a, b, sxy);
    }
    float r = 0.f;
    #pragma unroll
    for (int j = 0; j < WPT; j++) {
        r += ssim_win(P, Q, sxx, syy, sxy, c1, c1d, c2a, c2b);
        if (j < WPT - 1) {
            float ao = xv[j], an = xv[j + WIN];
            float bo = yv[j], bn = yv[j + WIN];
            P += an - ao;
            Q += bn - bo;
            sxx += fmaf(an, an, -(ao * ao));
            syy += fmaf(bn, bn, -(bo * bo));
            sxy += fmaf(an, bn, -(ao * bo));
        }
    }
    return r;
}

__global__ __launch_bounds__(BLK) void kmax_partial(const float* __restrict__ y, int n,
                                                    float* __restrict__ outMax) {
    const int gid = blockIdx.x * BLK + threadIdx.x;
    const int n4 = n >> 2;
    const float4* y4 = (const float4*)y;
    float m0 = -__builtin_huge_valf(), m1 = m0;
    int i = gid;
    for (; i + GSTRIDE < n4; i += 2 * GSTRIDE) {
        float4 a = y4[i];
        float4 b = y4[i + GSTRIDE];
        m0 = fmaxf(m0, max4(a));
        m1 = fmaxf(m1, max4(b));
    }
    for (; i < n4; i += GSTRIDE) m0 = fmaxf(m0, max4(y4[i]));
    for (int j = (n4 << 2) + gid; j < n; j += GSTRIDE) m0 = fmaxf(m0, y[j]);
    float m = fmaxf(m0, m1);
    #pragma unroll
    for (int off = 32; off; off >>= 1) m = fmaxf(m, __shfl_xor(m, off));
    __shared__ float sm[4];
    if ((threadIdx.x & 63) == 0) sm[threadIdx.x >> 6] = m;
    __syncthreads();
    if (threadIdx.x == 0)
        outMax[blockIdx.x] = fmaxf(fmaxf(sm[0], sm[1]), fmaxf(sm[2], sm[3]));
}

__global__ __launch_bounds__(SBLK) void kssim(const float* __restrict__ x,
                                              const float* __restrict__ y,
                                              const float* __restrict__ partMax, int n,
                                              int ninterior, int nfull, int rem,
                                              float* __restrict__ blockSums) {
    const int tid = threadIdx.x;
    const int gid = blockIdx.x * SBLK + tid;
    __shared__ float sm[SBLK / 64];

    // ---- issue prologue item's loads FIRST: memory stream starts immediately,
    //      latency hides under the partMax pre-reduce below ----
    float4 ax0, ax1, ax2, ax3, ay0, ay1, ay2, ay3;
    int g = gid;
    if (g < ninterior) {
        const float4* px = (const float4*)(x + g * WPT);   // 32B-aligned
        ax0 = px[0]; ax1 = px[1]; ax2 = px[2]; ax3 = px[3];
        const float4* py = (const float4*)(y + g * WPT);
        ay0 = py[0]; ay1 = py[1]; ay2 = py[2]; ay3 = py[3];
    }

    // ---- block-local finalize of max(y) (8 KB, L2/L3-hot; 4 loads/thread) ----
    float mm = -__builtin_huge_valf();
    #pragma unroll
    for (int i = 0; i < NB / SBLK; i++) mm = fmaxf(mm, partMax[i * SBLK + tid]);
    #pragma unroll
    for (int off = 32; off; off >>= 1) mm = fmaxf(mm, __shfl_xor(mm, off));
    if ((tid & 63) == 0) sm[tid >> 6] = mm;
    __syncthreads();
    float dr = sm[0];
    #pragma unroll
    for (int i = 1; i < SBLK / 64; i++) dr = fmaxf(dr, sm[i]);
    const float C1 = (0.01f * dr) * (0.01f * dr);
    const float C2 = (0.03f * dr) * (0.03f * dr);
    const float c1  = 49.0f * C1;
    const float c1d = 2.0f * c1;
    const float c2a = 21.0f * C2;
    const float c2b = 42.0f * C2;

    // ---- fixed-trip-count depth-1 prefetch pipeline ----
    float acc = 0.0f;
    for (int k = 0; k < nfull; k++) {
        const int gn = g + GSTRIDE;
        const bool nextExists = (k + 1 < nfull) || (gid < rem);
        float4 bx0, bx1, bx2, bx3, by0, by1, by2, by3;
        if (nextExists) {                 // issue next item's loads before compute
            const float4* px = (const float4*)(x + gn * WPT);
            bx0 = px[0]; bx1 = px[1]; bx2 = px[2]; bx3 = px[3];
            const float4* py = (const float4*)(y + gn * WPT);
            by0 = py[0]; by1 = py[1]; by2 = py[2]; by3 = py[3];
        }
        acc += compute_item(ax0, ax1, ax2, ax3, ay0, ay1, ay2, ay3, c1, c1d, c2a, c2b);
        ax0 = bx0; ax1 = bx1; ax2 = bx2; ax3 = bx3;
        ay0 = by0; ay1 = by1; ay2 = by2; ay3 = by3;
        g = gn;
    }
    if (gid < rem)   // prefetched tail item (or the prologue item when nfull==0)
        acc += compute_item(ax0, ax1, ax2, ax3, ay0, ay1, ay2, ay3, c1, c1d, c2a, c2b);

    // tail windows not covered by items (< WPT+1 of them): thread 0, scalar
    if (gid == 0) {
        const int nw = n - (WIN - 1);
        for (int w = ninterior * WPT; w < nw; ++w) {
            float P = 0.f, Q = 0.f, sxx = 0.f, syy = 0.f, sxy = 0.f;
            for (int k = 0; k < WIN; k++) {
                float a = x[w + k], b = y[w + k];
                P += a; Q += b;
                sxx = fmaf(a, a, sxx);
                syy = fmaf(b, b, syy);
                sxy = fmaf(a, b, sxy);
            }
            acc += ssim_win(P, Q, sxx, syy, sxy, c1, c1d, c2a, c2b);
        }
    }

    // ---- block reduce -> blockSums (no atomics: they serialize block retire) ----
    #pragma unroll
    for (int off = 32; off; off >>= 1) acc += __shfl_xor(acc, off);
    __syncthreads();          // sm reused
    if ((tid & 63) == 0) sm[tid >> 6] = acc;
    __syncthreads();
    if (tid == 0) {
        float bs = sm[0];
        #pragma unroll
        for (int i = 1; i < SBLK / 64; i++) bs += sm[i];
        blockSums[blockIdx.x] = bs;
    }
}

__global__ __launch_bounds__(FBLK) void kfinal(const float* __restrict__ blockSums, int nb,
                                               float* __restrict__ out, int nw) {
    double s = 0.0;
    for (int i = threadIdx.x; i < nb; i += FBLK) s += (double)blockSums[i];
    #pragma unroll
    for (int off = 32; off; off >>= 1) s += __shfl_xor(s, off);
    __shared__ double sd[FBLK / 64];
    if ((threadIdx.x & 63) == 0) sd[threadIdx.x >> 6] = s;
    __syncthreads();
    if (threadIdx.x == 0) {
        double t = 0.0;
        #pragma unroll
        for (int i = 0; i < FBLK / 64; i++) t += sd[i];
        out[0] = (float)(t / (double)nw);
    }
}

extern "C" void kernel_launch(void* const* d_in, const int* in_sizes, int n_in,
                              void* d_out, int out_size, void* d_ws, size_t ws_size,
                              hipStream_t stream) {
    const float* x = (const float*)d_in[0];
    const float* y = (const float*)d_in[1];
    float* out = (float*)d_out;
    int n = in_sizes[0];
    int nw = n - (WIN - 1);
    int ninterior = (n >= 16) ? ((n - 16) / WPT + 1) : 0;  // item g needs floats [8g,8g+16)
    int nfull = ninterior / GSTRIDE;
    int rem   = ninterior - nfull * GSTRIDE;

    float* wsf = (float*)d_ws;
    float* partMax   = wsf;          // NB floats
    float* blockSums = wsf + NB;     // SNB floats

    kmax_partial<<<NB, BLK, 0, stream>>>(y, n, partMax);
    kssim<<<SNB, SBLK, 0, stream>>>(x, y, partMax, n, ninterior, nfull, rem, blockSums);
    kfinal<<<1, FBLK, 0, stream>>>(blockSums, SNB, out, nw);
}